// Round 1
// baseline (579.120 us; speedup 1.0000x reference)
//
#include <hip/hip_runtime.h>

#define N_NODES 40000
#define N_EDGES 640000
#define DIM 128
#define N_LAYERS 3

// ---------------- preprocessing: CSR by dst ----------------

__global__ void hist_kernel(const int* __restrict__ dst, int* __restrict__ deg) {
    int i = blockIdx.x * blockDim.x + threadIdx.x;
    if (i < N_EDGES) atomicAdd(&deg[dst[i]], 1);
}

// single-block exclusive scan over 40000 degrees; also writes inv_deg
__global__ void scan_kernel(const int* __restrict__ deg, int* __restrict__ offsets,
                            float* __restrict__ inv_deg) {
    __shared__ int sdata[1024];
    __shared__ int carry_s;
    if (threadIdx.x == 0) carry_s = 0;
    __syncthreads();
    for (int base = 0; base < N_NODES; base += 1024) {
        int i = base + threadIdx.x;
        int v = (i < N_NODES) ? deg[i] : 0;
        if (i < N_NODES) inv_deg[i] = 1.0f / fmaxf((float)v, 1.0f);
        sdata[threadIdx.x] = v;
        __syncthreads();
        for (int off = 1; off < 1024; off <<= 1) {
            int t = (threadIdx.x >= off) ? sdata[threadIdx.x - off] : 0;
            __syncthreads();
            sdata[threadIdx.x] += t;
            __syncthreads();
        }
        if (i < N_NODES) offsets[i] = carry_s + sdata[threadIdx.x] - v;  // exclusive
        __syncthreads();
        if (threadIdx.x == 1023) carry_s += sdata[1023];
        __syncthreads();
    }
    if (threadIdx.x == 0) offsets[N_NODES] = carry_s;
}

__global__ void scatter_kernel(const int* __restrict__ src, const int* __restrict__ dst,
                               const int* __restrict__ offsets, int* __restrict__ cursor,
                               int* __restrict__ csr_src) {
    int i = blockIdx.x * blockDim.x + threadIdx.x;
    if (i < N_EDGES) {
        int d = dst[i];
        int pos = atomicAdd(&cursor[d], 1);
        csr_src[offsets[d] + pos] = src[i];
    }
}

// ---------------- per-layer: mean aggregation (gather over CSR) ----------------
// one wave (64 lanes) per node; each lane owns 2 feature columns (float2 -> 512B/row coalesced)
__global__ void agg_kernel(const float* __restrict__ h, const int* __restrict__ offsets,
                           const int* __restrict__ csr_src, const float* __restrict__ inv_deg,
                           float* __restrict__ agg) {
    int node = (blockIdx.x * blockDim.x + threadIdx.x) >> 6;
    int lane = threadIdx.x & 63;
    if (node >= N_NODES) return;
    int e0 = offsets[node], e1 = offsets[node + 1];
    float ax = 0.f, ay = 0.f;
    const float2* h2 = (const float2*)h;
    for (int e = e0; e < e1; ++e) {
        int s = csr_src[e];               // wave-uniform -> broadcast
        float2 v = h2[s * 64 + lane];
        ax += v.x; ay += v.y;
    }
    float w = inv_deg[node];
    ((float2*)agg)[node * 64 + lane] = make_float2(ax * w, ay * w);
}

// ---------------- per-layer: fused dual GEMM + bias + relu ----------------
// out[r] = hin[r] @ Wself + agg[r] @ Wneigh + b   (optionally relu)
// tile 64 rows x 128 cols, 256 threads, each thread 8 rows x 4 cols.
// In-place safe (hin may == hout): each block reads only its own rows into LDS
// before writing them.
__global__ __launch_bounds__(256) void gemm_kernel(
    const float* hin, const float* __restrict__ agg,
    const float* __restrict__ w_self, const float* __restrict__ w_neigh,
    const float* __restrict__ bias, float* hout, int relu) {
    __shared__ float sh_in[64][DIM];   // 32 KB
    __shared__ float sh_ag[64][DIM];   // 32 KB
    __shared__ float sh_w[32][DIM];    // 16 KB
    const int row0 = blockIdx.x * 64;
    const int tid = threadIdx.x;

    // stage input tiles (8 float4 per thread per tile)
    for (int i = tid; i < 64 * (DIM / 4); i += 256) {
        int r = i / (DIM / 4), c4 = i % (DIM / 4);
        ((float4*)sh_in[r])[c4] = ((const float4*)(hin + (size_t)(row0 + r) * DIM))[c4];
        ((float4*)sh_ag[r])[c4] = ((const float4*)(agg + (size_t)(row0 + r) * DIM))[c4];
    }

    const int cg = tid & 31;   // col group: cols cg*4 .. cg*4+3
    const int rg = tid >> 5;   // row group: rows rg*8 .. rg*8+7
    float acc[8][4];
#pragma unroll
    for (int r = 0; r < 8; ++r)
#pragma unroll
        for (int c = 0; c < 4; ++c) acc[r][c] = 0.f;

    for (int half = 0; half < 2; ++half) {
        const float* W = half ? w_neigh : w_self;
        float(*IN)[DIM] = half ? sh_ag : sh_in;
        for (int kb = 0; kb < DIM; kb += 32) {
            __syncthreads();
            // stage W[kb..kb+31][0..127] (4 float4 per thread)
            for (int i = tid; i < 32 * (DIM / 4); i += 256) {
                int k = i / (DIM / 4), c4 = i % (DIM / 4);
                ((float4*)sh_w[k])[c4] = ((const float4*)(W + (size_t)(kb + k) * DIM))[c4];
            }
            __syncthreads();
#pragma unroll 8
            for (int k = 0; k < 32; ++k) {
                float4 wv = ((float4*)sh_w[k])[cg];
#pragma unroll
                for (int r = 0; r < 8; ++r) {
                    float xv = IN[rg * 8 + r][kb + k];   // broadcast within wave
                    acc[r][0] = fmaf(xv, wv.x, acc[r][0]);
                    acc[r][1] = fmaf(xv, wv.y, acc[r][1]);
                    acc[r][2] = fmaf(xv, wv.z, acc[r][2]);
                    acc[r][3] = fmaf(xv, wv.w, acc[r][3]);
                }
            }
        }
    }
    __syncthreads();

    float4 bv = ((const float4*)bias)[cg];
#pragma unroll
    for (int r = 0; r < 8; ++r) {
        float4 o = make_float4(acc[r][0] + bv.x, acc[r][1] + bv.y,
                               acc[r][2] + bv.z, acc[r][3] + bv.w);
        if (relu) {
            o.x = fmaxf(o.x, 0.f); o.y = fmaxf(o.y, 0.f);
            o.z = fmaxf(o.z, 0.f); o.w = fmaxf(o.w, 0.f);
        }
        ((float4*)(hout + (size_t)(row0 + rg * 8 + r) * DIM))[cg] = o;
    }
}

// ---------------- launch ----------------

extern "C" void kernel_launch(void* const* d_in, const int* in_sizes, int n_in,
                              void* d_out, int out_size, void* d_ws, size_t ws_size,
                              hipStream_t stream) {
    const float* x      = (const float*)d_in[0];
    const int*   src    = (const int*)d_in[1];
    const int*   dst    = (const int*)d_in[2];
    const float* w_self = (const float*)d_in[3];
    const float* w_neigh= (const float*)d_in[4];
    const float* b      = (const float*)d_in[5];
    float* out = (float*)d_out;

    // workspace carve (~23.7 MB)
    char* ws = (char*)d_ws;
    float* agg     = (float*)ws;                       ws += (size_t)N_NODES * DIM * 4;
    int*   deg     = (int*)ws;                         ws += (size_t)N_NODES * 4;
    int*   offsets = (int*)ws;                         ws += (size_t)(N_NODES + 1) * 4;
    int*   cursor  = (int*)ws;                         ws += (size_t)N_NODES * 4;
    int*   csr_src = (int*)ws;                         ws += (size_t)N_EDGES * 4;
    float* inv_deg = (float*)ws;

    // zero deg + offsets + cursor in one shot (offsets overwritten by scan anyway)
    hipMemsetAsync(deg, 0, (size_t)(N_NODES + (N_NODES + 1) + N_NODES) * 4, stream);

    hist_kernel<<<(N_EDGES + 255) / 256, 256, 0, stream>>>(dst, deg);
    scan_kernel<<<1, 1024, 0, stream>>>(deg, offsets, inv_deg);
    scatter_kernel<<<(N_EDGES + 255) / 256, 256, 0, stream>>>(src, dst, offsets, cursor, csr_src);

    const float* hin = x;
    for (int l = 0; l < N_LAYERS; ++l) {
        agg_kernel<<<(N_NODES * 64) / 256, 256, 0, stream>>>(hin, offsets, csr_src, inv_deg, agg);
        gemm_kernel<<<N_NODES / 64, 256, 0, stream>>>(
            hin, agg, w_self + (size_t)l * DIM * DIM, w_neigh + (size_t)l * DIM * DIM,
            b + (size_t)l * DIM, out, (l < N_LAYERS - 1) ? 1 : 0);
        hin = out;  // in-place for layers 1,2
    }
}

// Round 2
// 429.890 us; speedup vs baseline: 1.3471x; 1.3471x over previous
//
#include <hip/hip_runtime.h>

#define N_NODES 40000
#define N_EDGES 640000
#define DIM 128
#define N_LAYERS 3

typedef __attribute__((ext_vector_type(8))) short bf16x8_t;
typedef __attribute__((ext_vector_type(4))) float f32x4_t;

__device__ __forceinline__ unsigned short f2bf(float x) {
    unsigned int u = __float_as_uint(x);
    return (unsigned short)((u + 0x7FFF + ((u >> 16) & 1)) >> 16);  // RNE
}
__device__ __forceinline__ float bf2f(unsigned short h) {
    return __uint_as_float(((unsigned int)h) << 16);
}

// ---------------- preprocessing: CSR by dst ----------------

__global__ void hist_kernel(const int* __restrict__ dst, int* __restrict__ deg) {
    int i = blockIdx.x * blockDim.x + threadIdx.x;
    if (i < N_EDGES) atomicAdd(&deg[dst[i]], 1);
}

// multi-block scan, phase 1: per-256 block scan + block sums + inv_deg
__global__ void scan1_kernel(const int* __restrict__ deg, int* __restrict__ offsets,
                             float* __restrict__ inv_deg, int* __restrict__ bsum) {
    __shared__ int sd[256];
    int t = threadIdx.x, i = blockIdx.x * 256 + t;
    int v = (i < N_NODES) ? deg[i] : 0;
    if (i < N_NODES) inv_deg[i] = 1.0f / fmaxf((float)v, 1.0f);
    sd[t] = v;
    __syncthreads();
#pragma unroll
    for (int off = 1; off < 256; off <<= 1) {
        int x = (t >= off) ? sd[t - off] : 0;
        __syncthreads();
        sd[t] += x;
        __syncthreads();
    }
    if (i < N_NODES) offsets[i] = sd[t] - v;  // block-local exclusive
    if (t == 255) bsum[blockIdx.x] = sd[255];
}

// phase 2: exclusive scan of the 157 block sums (one small block)
__global__ void scan2_kernel(const int* __restrict__ bsum, int* __restrict__ boff) {
    __shared__ int sd[256];
    const int nb = (N_NODES + 255) / 256;
    int t = threadIdx.x;
    int v = (t < nb) ? bsum[t] : 0;
    sd[t] = v;
    __syncthreads();
#pragma unroll
    for (int off = 1; off < 256; off <<= 1) {
        int x = (t >= off) ? sd[t - off] : 0;
        __syncthreads();
        sd[t] += x;
        __syncthreads();
    }
    if (t < nb) boff[t] = sd[t] - v;
}

// phase 3: add block offsets, emit total
__global__ void scan3_kernel(int* __restrict__ offsets, const int* __restrict__ deg,
                             const int* __restrict__ boff) {
    int i = blockIdx.x * 256 + threadIdx.x;
    if (i < N_NODES) {
        int o = offsets[i] + boff[blockIdx.x];
        offsets[i] = o;
        if (i == N_NODES - 1) offsets[N_NODES] = o + deg[i];
    }
}

__global__ void scatter_kernel(const int* __restrict__ src, const int* __restrict__ dst,
                               const int* __restrict__ offsets, int* __restrict__ cursor,
                               int* __restrict__ csr_src) {
    int i = blockIdx.x * blockDim.x + threadIdx.x;
    if (i < N_EDGES) {
        int d = dst[i];
        int pos = atomicAdd(&cursor[d], 1);
        csr_src[offsets[d] + pos] = src[i];
    }
}

// ---------------- weight prep: W[k][n] fp32 -> Wt[n][k] bf16 hi/lo ----------------
__global__ void wprep_kernel(const float* __restrict__ w_self, const float* __restrict__ w_neigh,
                             unsigned short* __restrict__ wt_hi, unsigned short* __restrict__ wt_lo) {
    int i = blockIdx.x * blockDim.x + threadIdx.x;  // [ls][n][k]
    if (i >= N_LAYERS * 2 * DIM * DIM) return;
    int k = i & (DIM - 1);
    int n = (i >> 7) & (DIM - 1);
    int ls = i >> 14;
    int l = ls >> 1, s = ls & 1;
    const float* W = (s ? w_neigh : w_self) + (size_t)l * DIM * DIM;
    float v = W[k * DIM + n];
    unsigned short h = f2bf(v);
    wt_hi[i] = h;
    wt_lo[i] = f2bf(v - bf2f(h));
}

// ---------------- x -> bf16 hi/lo split ----------------
__global__ void split_kernel(const float* __restrict__ in, unsigned short* __restrict__ hi,
                             unsigned short* __restrict__ lo) {
    int i = blockIdx.x * blockDim.x + threadIdx.x;
    if (i >= N_NODES * DIM / 4) return;
    float4 v = ((const float4*)in)[i];
    ushort4 H, L;
    H.x = f2bf(v.x); L.x = f2bf(v.x - bf2f(H.x));
    H.y = f2bf(v.y); L.y = f2bf(v.y - bf2f(H.y));
    H.z = f2bf(v.z); L.z = f2bf(v.z - bf2f(H.z));
    H.w = f2bf(v.w); L.w = f2bf(v.w - bf2f(H.w));
    ((ushort4*)hi)[i] = H;
    ((ushort4*)lo)[i] = L;
}

// ---------------- mean aggregation: fp32 gather, bf16 hi/lo split output ----------------
// one wave per node; lane owns 2 cols (float2 -> 512B/row coalesced)
__global__ void agg_kernel(const float* __restrict__ h, const int* __restrict__ offsets,
                           const int* __restrict__ csr_src, const float* __restrict__ inv_deg,
                           unsigned short* __restrict__ agg_hi, unsigned short* __restrict__ agg_lo) {
    int node = (blockIdx.x * blockDim.x + threadIdx.x) >> 6;
    int lane = threadIdx.x & 63;
    if (node >= N_NODES) return;
    int e0 = offsets[node], e1 = offsets[node + 1];
    float ax = 0.f, ay = 0.f;
    const float2* h2 = (const float2*)h;
    for (int e = e0; e < e1; ++e) {
        int s = csr_src[e];
        float2 v = h2[(size_t)s * 64 + lane];
        ax += v.x; ay += v.y;
    }
    float w = inv_deg[node];
    ax *= w; ay *= w;
    unsigned short hx = f2bf(ax), hy = f2bf(ay);
    unsigned short lx = f2bf(ax - bf2f(hx)), ly = f2bf(ay - bf2f(hy));
    int idx = node * 64 + lane;
    ((ushort2*)agg_hi)[idx] = make_ushort2(hx, hy);
    ((ushort2*)agg_lo)[idx] = make_ushort2(lx, ly);
}

// ---------------- fused dual GEMM via split-bf16 MFMA ----------------
// out = h @ Wself + agg @ Wneigh + b, each GEMM as AhBh + AhBl + AlBh (fp32-equivalent).
// Block: 256 thr = 4 waves, 128 rows x 128 cols. Wave: 32 rows (2 rt-tiles) x 8 jt-tiles.
// A-frags loaded straight from global in MFMA layout; W (hi/lo) staged in LDS per k-half.
#define LDSK 72  // 64-k half + 8 pad shorts -> 2-way-max bank aliasing (free)
__global__ __launch_bounds__(256) void gemm_kernel(
    const unsigned short* __restrict__ h_hi, const unsigned short* __restrict__ h_lo,
    const unsigned short* __restrict__ agg_hi, const unsigned short* __restrict__ agg_lo,
    const unsigned short* __restrict__ wt_hi, const unsigned short* __restrict__ wt_lo,
    const float* __restrict__ bias, float* __restrict__ fout,
    unsigned short* __restrict__ o_hi, unsigned short* __restrict__ o_lo,
    int write_bf16, int relu) {
    __shared__ unsigned short sWhi[DIM][LDSK];  // 18 KB
    __shared__ unsigned short sWlo[DIM][LDSK];  // 18 KB
    const int tid = threadIdx.x;
    const int wave = tid >> 6, lane = tid & 63;
    const int quad = lane >> 4, m = lane & 15;
    const int rowW = blockIdx.x * 128 + wave * 32;

    f32x4_t acc[2][8];
#pragma unroll
    for (int a = 0; a < 2; ++a)
#pragma unroll
        for (int b = 0; b < 8; ++b) acc[a][b] = {0.f, 0.f, 0.f, 0.f};

    for (int s = 0; s < 2; ++s) {
        const unsigned short* Ahi = s ? agg_hi : h_hi;
        const unsigned short* Alo = s ? agg_lo : h_lo;
        const unsigned short* Whi = wt_hi + s * DIM * DIM;
        const unsigned short* Wlo = wt_lo + s * DIM * DIM;
        for (int kh = 0; kh < 2; ++kh) {
            __syncthreads();  // previous compute done before restage
#pragma unroll
            for (int c4 = 0; c4 < 4; ++c4) {
                int c = (c4 << 8) + tid;        // 1024 16B-chunks per matrix
                int n = c >> 3, part = c & 7;   // row n, 16B chunk within 64-k half
                int go = n * DIM + kh * 64 + part * 8;
                *(bf16x8_t*)&sWhi[n][part * 8] = *(const bf16x8_t*)&Whi[go];
                *(bf16x8_t*)&sWlo[n][part * 8] = *(const bf16x8_t*)&Wlo[go];
            }
            __syncthreads();
#pragma unroll
            for (int k2 = 0; k2 < 2; ++k2) {
                // register-cache B-frags for this 32-k step: B[k][n], lane holds n=m, k=quad*8+j
                bf16x8_t Bh[8], Bl[8];
#pragma unroll
                for (int jt = 0; jt < 8; ++jt) {
                    int n = jt * 16 + m;
                    int ko = k2 * 32 + quad * 8;
                    Bh[jt] = *(const bf16x8_t*)&sWhi[n][ko];
                    Bl[jt] = *(const bf16x8_t*)&sWlo[n][ko];
                }
                const int kg = kh * 64 + k2 * 32 + quad * 8;  // global k for A-frag
#pragma unroll
                for (int rt = 0; rt < 2; ++rt) {
                    int r = rowW + rt * 16 + m;
                    r = (r < N_NODES) ? r : (N_NODES - 1);  // clamp; stores guarded later
                    size_t aoff = (size_t)r * DIM + kg;
                    bf16x8_t ah = *(const bf16x8_t*)&Ahi[aoff];
                    bf16x8_t al = *(const bf16x8_t*)&Alo[aoff];
#pragma unroll
                    for (int jt = 0; jt < 8; ++jt) {
                        acc[rt][jt] = __builtin_amdgcn_mfma_f32_16x16x32_bf16(ah, Bh[jt], acc[rt][jt], 0, 0, 0);
                        acc[rt][jt] = __builtin_amdgcn_mfma_f32_16x16x32_bf16(ah, Bl[jt], acc[rt][jt], 0, 0, 0);
                        acc[rt][jt] = __builtin_amdgcn_mfma_f32_16x16x32_bf16(al, Bh[jt], acc[rt][jt], 0, 0, 0);
                    }
                }
            }
        }
    }

    // epilogue: C/D layout col=lane&15, row=quad*4+reg  [m89-verified]
#pragma unroll
    for (int rt = 0; rt < 2; ++rt)
#pragma unroll
        for (int jt = 0; jt < 8; ++jt) {
            int col = jt * 16 + m;
            float bv = bias[col];
#pragma unroll
            for (int r4 = 0; r4 < 4; ++r4) {
                int row = rowW + rt * 16 + quad * 4 + r4;
                if (row >= N_NODES) continue;
                float v = acc[rt][jt][r4] + bv;
                if (relu) v = fmaxf(v, 0.f);
                fout[(size_t)row * DIM + col] = v;
                if (write_bf16) {
                    unsigned short h = f2bf(v);
                    o_hi[(size_t)row * DIM + col] = h;
                    o_lo[(size_t)row * DIM + col] = f2bf(v - bf2f(h));
                }
            }
        }
}

// ---------------- launch ----------------

extern "C" void kernel_launch(void* const* d_in, const int* in_sizes, int n_in,
                              void* d_out, int out_size, void* d_ws, size_t ws_size,
                              hipStream_t stream) {
    const float* x      = (const float*)d_in[0];
    const int*   src    = (const int*)d_in[1];
    const int*   dst    = (const int*)d_in[2];
    const float* w_self = (const float*)d_in[3];
    const float* w_neigh= (const float*)d_in[4];
    const float* b      = (const float*)d_in[5];
    float* out = (float*)d_out;

    // workspace carve (~65 MB)
    char* ws = (char*)d_ws;
    float* hbuf            = (float*)ws;          ws += (size_t)N_NODES * DIM * 4;
    unsigned short* h_hi   = (unsigned short*)ws; ws += (size_t)N_NODES * DIM * 2;
    unsigned short* h_lo   = (unsigned short*)ws; ws += (size_t)N_NODES * DIM * 2;
    unsigned short* agg_hi = (unsigned short*)ws; ws += (size_t)N_NODES * DIM * 2;
    unsigned short* agg_lo = (unsigned short*)ws; ws += (size_t)N_NODES * DIM * 2;
    unsigned short* wt_hi  = (unsigned short*)ws; ws += (size_t)N_LAYERS * 2 * DIM * DIM * 2;
    unsigned short* wt_lo  = (unsigned short*)ws; ws += (size_t)N_LAYERS * 2 * DIM * DIM * 2;
    int*   deg     = (int*)ws;  ws += (size_t)N_NODES * 4;
    int*   offsets = (int*)ws;  ws += (size_t)(N_NODES + 4) * 4;
    int*   cursor  = (int*)ws;  ws += (size_t)N_NODES * 4;
    int*   csr_src = (int*)ws;  ws += (size_t)N_EDGES * 4;
    float* inv_deg = (float*)ws; ws += (size_t)N_NODES * 4;
    int*   bsum    = (int*)ws;  ws += 256 * 4;
    int*   boff    = (int*)ws;

    const int NB = (N_NODES + 255) / 256;  // 157

    // zero deg + offsets + cursor (contiguous region)
    hipMemsetAsync(deg, 0, (size_t)(N_NODES + (N_NODES + 4) + N_NODES) * 4, stream);

    hist_kernel<<<(N_EDGES + 255) / 256, 256, 0, stream>>>(dst, deg);
    scan1_kernel<<<NB, 256, 0, stream>>>(deg, offsets, inv_deg, bsum);
    scan2_kernel<<<1, 256, 0, stream>>>(bsum, boff);
    scan3_kernel<<<NB, 256, 0, stream>>>(offsets, deg, boff);
    scatter_kernel<<<(N_EDGES + 255) / 256, 256, 0, stream>>>(src, dst, offsets, cursor, csr_src);
    wprep_kernel<<<(N_LAYERS * 2 * DIM * DIM + 255) / 256, 256, 0, stream>>>(w_self, w_neigh, wt_hi, wt_lo);
    split_kernel<<<(N_NODES * DIM / 4 + 255) / 256, 256, 0, stream>>>(x, h_hi, h_lo);

    const int GEMM_BLOCKS = (N_NODES + 127) / 128;  // 313
    for (int l = 0; l < N_LAYERS; ++l) {
        const float* hsrc = (l == 0) ? x : hbuf;
        agg_kernel<<<(N_NODES * 64 + 255) / 256, 256, 0, stream>>>(
            hsrc, offsets, csr_src, inv_deg, agg_hi, agg_lo);
        int last = (l == N_LAYERS - 1);
        gemm_kernel<<<GEMM_BLOCKS, 256, 0, stream>>>(
            h_hi, h_lo, agg_hi, agg_lo,
            wt_hi + (size_t)l * 2 * DIM * DIM, wt_lo + (size_t)l * 2 * DIM * DIM,
            b + (size_t)l * DIM,
            last ? out : hbuf, h_hi, h_lo,
            last ? 0 : 1, last ? 0 : 1);
    }
}

// Round 3
// 306.537 us; speedup vs baseline: 1.8892x; 1.4024x over previous
//
#include <hip/hip_runtime.h>

#define N_NODES 40000
#define N_EDGES 640000
#define DIM 128
#define N_LAYERS 3

typedef __attribute__((ext_vector_type(8))) short bf16x8_t;
typedef __attribute__((ext_vector_type(4))) float f32x4_t;

__device__ __forceinline__ unsigned short f2bf(float x) {
    unsigned int u = __float_as_uint(x);
    return (unsigned short)((u + 0x7FFF + ((u >> 16) & 1)) >> 16);  // RNE
}
__device__ __forceinline__ float bf2f(unsigned short h) {
    return __uint_as_float(((unsigned int)h) << 16);
}

// ---------------- preprocessing: CSR by dst ----------------

__global__ void hist_kernel(const int* __restrict__ dst, int* __restrict__ deg) {
    int i = blockIdx.x * blockDim.x + threadIdx.x;
    if (i < N_EDGES) atomicAdd(&deg[dst[i]], 1);
}

__global__ void scan1_kernel(const int* __restrict__ deg, int* __restrict__ offsets,
                             float* __restrict__ inv_deg, int* __restrict__ bsum) {
    __shared__ int sd[256];
    int t = threadIdx.x, i = blockIdx.x * 256 + t;
    int v = (i < N_NODES) ? deg[i] : 0;
    if (i < N_NODES) inv_deg[i] = 1.0f / fmaxf((float)v, 1.0f);
    sd[t] = v;
    __syncthreads();
#pragma unroll
    for (int off = 1; off < 256; off <<= 1) {
        int x = (t >= off) ? sd[t - off] : 0;
        __syncthreads();
        sd[t] += x;
        __syncthreads();
    }
    if (i < N_NODES) offsets[i] = sd[t] - v;  // block-local exclusive
    if (t == 255) bsum[blockIdx.x] = sd[255];
}

__global__ void scan2_kernel(const int* __restrict__ bsum, int* __restrict__ boff) {
    __shared__ int sd[256];
    const int nb = (N_NODES + 255) / 256;
    int t = threadIdx.x;
    int v = (t < nb) ? bsum[t] : 0;
    sd[t] = v;
    __syncthreads();
#pragma unroll
    for (int off = 1; off < 256; off <<= 1) {
        int x = (t >= off) ? sd[t - off] : 0;
        __syncthreads();
        sd[t] += x;
        __syncthreads();
    }
    if (t < nb) boff[t] = sd[t] - v;
}

__global__ void scan3_kernel(int* __restrict__ offsets, const int* __restrict__ deg,
                             const int* __restrict__ boff) {
    int i = blockIdx.x * 256 + threadIdx.x;
    if (i < N_NODES) {
        int o = offsets[i] + boff[blockIdx.x];
        offsets[i] = o;
        if (i == N_NODES - 1) offsets[N_NODES] = o + deg[i];
    }
}

__global__ void scatter_kernel(const int* __restrict__ src, const int* __restrict__ dst,
                               const int* __restrict__ offsets, int* __restrict__ cursor,
                               int* __restrict__ csr_src) {
    int i = blockIdx.x * blockDim.x + threadIdx.x;
    if (i < N_EDGES) {
        int d = dst[i];
        int pos = atomicAdd(&cursor[d], 1);
        csr_src[offsets[d] + pos] = src[i];
    }
}

// ---------------- weight prep: W[k][n] fp32 -> Wt[n][k] bf16 hi/lo ----------------
__global__ void wprep_kernel(const float* __restrict__ w_self, const float* __restrict__ w_neigh,
                             unsigned short* __restrict__ wt_hi, unsigned short* __restrict__ wt_lo) {
    int i = blockIdx.x * blockDim.x + threadIdx.x;  // [ls][n][k]
    if (i >= N_LAYERS * 2 * DIM * DIM) return;
    int k = i & (DIM - 1);
    int n = (i >> 7) & (DIM - 1);
    int ls = i >> 14;
    int l = ls >> 1, s = ls & 1;
    const float* W = (s ? w_neigh : w_self) + (size_t)l * DIM * DIM;
    float v = W[k * DIM + n];
    unsigned short h = f2bf(v);
    wt_hi[i] = h;
    wt_lo[i] = f2bf(v - bf2f(h));
}

// ---------------- x -> bf16 hi/lo split ----------------
__global__ void split_kernel(const float* __restrict__ in, unsigned short* __restrict__ hi,
                             unsigned short* __restrict__ lo) {
    int i = blockIdx.x * blockDim.x + threadIdx.x;
    if (i >= N_NODES * DIM / 4) return;
    float4 v = ((const float4*)in)[i];
    ushort4 H, L;
    H.x = f2bf(v.x); L.x = f2bf(v.x - bf2f(H.x));
    H.y = f2bf(v.y); L.y = f2bf(v.y - bf2f(H.y));
    H.z = f2bf(v.z); L.z = f2bf(v.z - bf2f(H.z));
    H.w = f2bf(v.w); L.w = f2bf(v.w - bf2f(H.w));
    ((ushort4*)hi)[i] = H;
    ((ushort4*)lo)[i] = L;
}

// ---------------- mean aggregation: bf16 gather (256B rows), fp32 accumulate ----------------
// one wave per node; 16 lanes per row (16B bf16x8 each), 4 edges per wave-instr,
// 2 row-loads in flight per loop iter (8 edges), shuffle-reduce across edge groups.
__global__ void agg_kernel(const unsigned short* __restrict__ h_hi,
                           const int* __restrict__ offsets,
                           const int* __restrict__ csr_src, const float* __restrict__ inv_deg,
                           unsigned short* __restrict__ agg_hi, unsigned short* __restrict__ agg_lo) {
    int node = (blockIdx.x * blockDim.x + threadIdx.x) >> 6;
    int lane = threadIdx.x & 63;
    if (node >= N_NODES) return;
    const int g = lane >> 4, c = lane & 15;  // edge-group, 16B column chunk
    int e0 = offsets[node], e1 = offsets[node + 1];
    float acc[8] = {0.f, 0.f, 0.f, 0.f, 0.f, 0.f, 0.f, 0.f};
    for (int base = e0; base < e1; base += 8) {
        int ea = base + g, eb = base + 4 + g;
        float fa = (ea < e1) ? 1.f : 0.f;
        float fb = (eb < e1) ? 1.f : 0.f;
        int sa = (ea < e1) ? csr_src[ea] : 0;
        int sb = (eb < e1) ? csr_src[eb] : 0;
        bf16x8_t va = *(const bf16x8_t*)&h_hi[(size_t)sa * DIM + c * 8];
        bf16x8_t vb = *(const bf16x8_t*)&h_hi[(size_t)sb * DIM + c * 8];
#pragma unroll
        for (int j = 0; j < 8; ++j) {
            acc[j] = fmaf(fa, bf2f((unsigned short)va[j]), acc[j]);
            acc[j] = fmaf(fb, bf2f((unsigned short)vb[j]), acc[j]);
        }
    }
#pragma unroll
    for (int j = 0; j < 8; ++j) {
        acc[j] += __shfl_xor(acc[j], 16, 64);
        acc[j] += __shfl_xor(acc[j], 32, 64);
    }
    if (g == 0) {
        float w = inv_deg[node];
        bf16x8_t H, L;
#pragma unroll
        for (int j = 0; j < 8; ++j) {
            float v = acc[j] * w;
            unsigned short hh = f2bf(v);
            H[j] = (short)hh;
            L[j] = (short)f2bf(v - bf2f(hh));
        }
        *(bf16x8_t*)&agg_hi[(size_t)node * DIM + c * 8] = H;
        *(bf16x8_t*)&agg_lo[(size_t)node * DIM + c * 8] = L;
    }
}

// ---------------- fused dual GEMM via split-bf16 MFMA ----------------
// out = h @ Wself + agg @ Wneigh + b, each GEMM as AhBh + AhBl + AlBh (fp32-equivalent).
// Block: 256 thr = 4 waves, 128 rows x 128 cols. Wave: 32 rows (2 rt-tiles) x 8 jt-tiles.
// A-frags loaded straight from global in MFMA layout; W (hi/lo) staged in LDS per k-half.
#define LDSK 72  // 64-k half + 8 pad shorts -> 2-way-max bank aliasing (free)
__global__ __launch_bounds__(256) void gemm_kernel(
    const unsigned short* __restrict__ h_hi, const unsigned short* __restrict__ h_lo,
    const unsigned short* __restrict__ agg_hi, const unsigned short* __restrict__ agg_lo,
    const unsigned short* __restrict__ wt_hi, const unsigned short* __restrict__ wt_lo,
    const float* __restrict__ bias, float* __restrict__ fout,
    unsigned short* __restrict__ o_hi, unsigned short* __restrict__ o_lo,
    int write_f32, int relu) {
    __shared__ unsigned short sWhi[DIM][LDSK];  // 18 KB
    __shared__ unsigned short sWlo[DIM][LDSK];  // 18 KB
    const int tid = threadIdx.x;
    const int wave = tid >> 6, lane = tid & 63;
    const int quad = lane >> 4, m = lane & 15;
    const int rowW = blockIdx.x * 128 + wave * 32;

    f32x4_t acc[2][8];
#pragma unroll
    for (int a = 0; a < 2; ++a)
#pragma unroll
        for (int b = 0; b < 8; ++b) acc[a][b] = {0.f, 0.f, 0.f, 0.f};

    for (int s = 0; s < 2; ++s) {
        const unsigned short* Ahi = s ? agg_hi : h_hi;
        const unsigned short* Alo = s ? agg_lo : h_lo;
        const unsigned short* Whi = wt_hi + s * DIM * DIM;
        const unsigned short* Wlo = wt_lo + s * DIM * DIM;
        for (int kh = 0; kh < 2; ++kh) {
            __syncthreads();  // previous compute done before restage
#pragma unroll
            for (int c4 = 0; c4 < 4; ++c4) {
                int c = (c4 << 8) + tid;        // 1024 16B-chunks per matrix
                int n = c >> 3, part = c & 7;   // row n, 16B chunk within 64-k half
                int go = n * DIM + kh * 64 + part * 8;
                *(bf16x8_t*)&sWhi[n][part * 8] = *(const bf16x8_t*)&Whi[go];
                *(bf16x8_t*)&sWlo[n][part * 8] = *(const bf16x8_t*)&Wlo[go];
            }
            __syncthreads();
#pragma unroll
            for (int k2 = 0; k2 < 2; ++k2) {
                bf16x8_t Bh[8], Bl[8];
#pragma unroll
                for (int jt = 0; jt < 8; ++jt) {
                    int n = jt * 16 + m;
                    int ko = k2 * 32 + quad * 8;
                    Bh[jt] = *(const bf16x8_t*)&sWhi[n][ko];
                    Bl[jt] = *(const bf16x8_t*)&sWlo[n][ko];
                }
                const int kg = kh * 64 + k2 * 32 + quad * 8;  // global k for A-frag
#pragma unroll
                for (int rt = 0; rt < 2; ++rt) {
                    int r = rowW + rt * 16 + m;
                    r = (r < N_NODES) ? r : (N_NODES - 1);  // clamp; stores guarded later
                    size_t aoff = (size_t)r * DIM + kg;
                    bf16x8_t ah = *(const bf16x8_t*)&Ahi[aoff];
                    bf16x8_t al = *(const bf16x8_t*)&Alo[aoff];
#pragma unroll
                    for (int jt = 0; jt < 8; ++jt) {
                        acc[rt][jt] = __builtin_amdgcn_mfma_f32_16x16x32_bf16(ah, Bh[jt], acc[rt][jt], 0, 0, 0);
                        acc[rt][jt] = __builtin_amdgcn_mfma_f32_16x16x32_bf16(ah, Bl[jt], acc[rt][jt], 0, 0, 0);
                        acc[rt][jt] = __builtin_amdgcn_mfma_f32_16x16x32_bf16(al, Bh[jt], acc[rt][jt], 0, 0, 0);
                    }
                }
            }
        }
    }

    // epilogue: C/D layout col=lane&15, row=quad*4+reg  [m89-verified]
#pragma unroll
    for (int rt = 0; rt < 2; ++rt)
#pragma unroll
        for (int jt = 0; jt < 8; ++jt) {
            int col = jt * 16 + m;
            float bv = bias[col];
#pragma unroll
            for (int r4 = 0; r4 < 4; ++r4) {
                int row = rowW + rt * 16 + quad * 4 + r4;
                if (row >= N_NODES) continue;
                float v = acc[rt][jt][r4] + bv;
                if (relu) v = fmaxf(v, 0.f);
                if (write_f32) {
                    fout[(size_t)row * DIM + col] = v;
                } else {
                    unsigned short h = f2bf(v);
                    o_hi[(size_t)row * DIM + col] = h;
                    o_lo[(size_t)row * DIM + col] = f2bf(v - bf2f(h));
                }
            }
        }
}

// ---------------- launch ----------------

extern "C" void kernel_launch(void* const* d_in, const int* in_sizes, int n_in,
                              void* d_out, int out_size, void* d_ws, size_t ws_size,
                              hipStream_t stream) {
    const float* x      = (const float*)d_in[0];
    const int*   src    = (const int*)d_in[1];
    const int*   dst    = (const int*)d_in[2];
    const float* w_self = (const float*)d_in[3];
    const float* w_neigh= (const float*)d_in[4];
    const float* b      = (const float*)d_in[5];
    float* out = (float*)d_out;

    // workspace carve (~45 MB)
    char* ws = (char*)d_ws;
    unsigned short* h_hi   = (unsigned short*)ws; ws += (size_t)N_NODES * DIM * 2;
    unsigned short* h_lo   = (unsigned short*)ws; ws += (size_t)N_NODES * DIM * 2;
    unsigned short* agg_hi = (unsigned short*)ws; ws += (size_t)N_NODES * DIM * 2;
    unsigned short* agg_lo = (unsigned short*)ws; ws += (size_t)N_NODES * DIM * 2;
    unsigned short* wt_hi  = (unsigned short*)ws; ws += (size_t)N_LAYERS * 2 * DIM * DIM * 2;
    unsigned short* wt_lo  = (unsigned short*)ws; ws += (size_t)N_LAYERS * 2 * DIM * DIM * 2;
    int*   deg     = (int*)ws;  ws += (size_t)N_NODES * 4;
    int*   offsets = (int*)ws;  ws += (size_t)(N_NODES + 4) * 4;
    int*   cursor  = (int*)ws;  ws += (size_t)N_NODES * 4;
    int*   csr_src = (int*)ws;  ws += (size_t)N_EDGES * 4;
    float* inv_deg = (float*)ws; ws += (size_t)N_NODES * 4;
    int*   bsum    = (int*)ws;  ws += 256 * 4;
    int*   boff    = (int*)ws;

    const int NB = (N_NODES + 255) / 256;  // 157

    hipMemsetAsync(deg, 0, (size_t)(N_NODES + (N_NODES + 4) + N_NODES) * 4, stream);

    hist_kernel<<<(N_EDGES + 255) / 256, 256, 0, stream>>>(dst, deg);
    scan1_kernel<<<NB, 256, 0, stream>>>(deg, offsets, inv_deg, bsum);
    scan2_kernel<<<1, 256, 0, stream>>>(bsum, boff);
    scan3_kernel<<<NB, 256, 0, stream>>>(offsets, deg, boff);
    scatter_kernel<<<(N_EDGES + 255) / 256, 256, 0, stream>>>(src, dst, offsets, cursor, csr_src);
    wprep_kernel<<<(N_LAYERS * 2 * DIM * DIM + 255) / 256, 256, 0, stream>>>(w_self, w_neigh, wt_hi, wt_lo);
    split_kernel<<<(N_NODES * DIM / 4 + 255) / 256, 256, 0, stream>>>(x, h_hi, h_lo);

    const int GEMM_BLOCKS = (N_NODES + 127) / 128;  // 313
    for (int l = 0; l < N_LAYERS; ++l) {
        agg_kernel<<<(N_NODES * 64 + 255) / 256, 256, 0, stream>>>(
            h_hi, offsets, csr_src, inv_deg, agg_hi, agg_lo);
        int last = (l == N_LAYERS - 1);
        gemm_kernel<<<GEMM_BLOCKS, 256, 0, stream>>>(
            h_hi, h_lo, agg_hi, agg_lo,
            wt_hi + (size_t)l * 2 * DIM * DIM, wt_lo + (size_t)l * 2 * DIM * DIM,
            b + (size_t)l * DIM,
            out, h_hi, h_lo,
            last ? 1 : 0, last ? 0 : 1);
    }
}